// Round 4
// baseline (3112.854 us; speedup 1.0000x reference)
//
#include <hip/hip_runtime.h>
#include <hip/hip_bf16.h>
#include <stdint.h>

// Problem constants: B=8,S=1024,D=1024,E=8,H=4096,top_k=2
#define TKN   8192
#define DD    1024
#define EE    8
#define HH    4096
#define TOPK  2
#define NASG  (TKN * TOPK)      // 16384 assignments

typedef unsigned short u16;
typedef __bf16 bf16x8 __attribute__((ext_vector_type(8)));
typedef float  f32x4  __attribute__((ext_vector_type(4)));

__device__ __forceinline__ u16 f2bf(float f) {
  __hip_bfloat16 h = __float2bfloat16(f);
  return __builtin_bit_cast(u16, h);
}

__device__ __forceinline__ void glds16(const void* g, void* l) {
  __builtin_amdgcn_global_load_lds(
      (__attribute__((address_space(1))) void*)g,
      (__attribute__((address_space(3))) void*)l, 16, 0, 0);
}

#define FENCE() asm volatile("" ::: "memory")
#define BAR()   do { FENCE(); __builtin_amdgcn_s_barrier(); FENCE(); } while (0)
#define VMCNT2() asm volatile("s_waitcnt vmcnt(2)" ::: "memory")
#define VMCNT0() asm volatile("s_waitcnt vmcnt(0)" ::: "memory")

// ---------------- transpose + f32->bf16 convert: [E][R][C] f32 -> [E][C][R] bf16
__global__ __launch_bounds__(256) void transpose_cvt_kernel(
    const float* __restrict__ src, u16* __restrict__ dst, int R, int C) {
  __shared__ float tile[32][33];
  int e = blockIdx.z;
  int c0 = blockIdx.x * 32, r0 = blockIdx.y * 32;
  int tx = threadIdx.x, ty = threadIdx.y;  // 32 x 8
  const float* s = src + (size_t)e * R * C;
  u16* d = dst + (size_t)e * R * C;
#pragma unroll
  for (int j = 0; j < 4; j++)
    tile[ty * 4 + j][tx] = s[(size_t)(r0 + ty * 4 + j) * C + c0 + tx];
  __syncthreads();
#pragma unroll
  for (int j = 0; j < 4; j++)
    d[(size_t)(c0 + ty * 4 + j) * R + r0 + tx] = f2bf(tile[tx][ty * 4 + j]);
}

// ---------------- router
__global__ __launch_bounds__(256) void router_kernel(
    const float* __restrict__ x, const float* __restrict__ noise,
    const float* __restrict__ Wg, const float* __restrict__ bg,
    const float* __restrict__ Wn, const float* __restrict__ bn,
    float* __restrict__ gating, u16* __restrict__ xb,
    int* __restrict__ sel_e, float* __restrict__ sel_g) {
  int t = blockIdx.x;
  int tid = threadIdx.x;
  float acc[16];
#pragma unroll
  for (int j = 0; j < 16; j++) acc[j] = 0.f;
  for (int i = tid; i < DD; i += 256) {
    float xv = x[(size_t)t * DD + i];
    xb[(size_t)t * DD + i] = f2bf(xv);
    const float4* g4 = (const float4*)(Wg + (size_t)i * EE);
    const float4* n4 = (const float4*)(Wn + (size_t)i * EE);
    float4 ga = g4[0], gb = g4[1];
    float4 na = n4[0], nb = n4[1];
    acc[0] += xv * ga.x;  acc[1] += xv * ga.y;  acc[2] += xv * ga.z;  acc[3] += xv * ga.w;
    acc[4] += xv * gb.x;  acc[5] += xv * gb.y;  acc[6] += xv * gb.z;  acc[7] += xv * gb.w;
    acc[8] += xv * na.x;  acc[9] += xv * na.y;  acc[10] += xv * na.z; acc[11] += xv * na.w;
    acc[12] += xv * nb.x; acc[13] += xv * nb.y; acc[14] += xv * nb.z; acc[15] += xv * nb.w;
  }
  __shared__ float red[4][16];
  int lane = tid & 63, wv = tid >> 6;
#pragma unroll
  for (int j = 0; j < 16; j++) {
    float v = acc[j];
    for (int o = 32; o > 0; o >>= 1) v += __shfl_down(v, o);
    acc[j] = v;
  }
  if (lane == 0) {
#pragma unroll
    for (int j = 0; j < 16; j++) red[wv][j] = acc[j];
  }
  __syncthreads();
  if (tid == 0) {
    float nz[EE];
#pragma unroll
    for (int e = 0; e < EE; e++) {
      float dg = red[0][e] + red[1][e] + red[2][e] + red[3][e] + bg[e];
      float dn = red[0][8 + e] + red[1][8 + e] + red[2][8 + e] + red[3][8 + e] + bn[e];
      float sp = fmaxf(dn, 0.f) + log1pf(expf(-fabsf(dn)));
      nz[e] = dg + noise[(size_t)t * EE + e] * sp;
    }
    int m1 = 0;
    for (int e = 1; e < EE; e++) if (nz[e] > nz[m1]) m1 = e;
    int m2 = (m1 == 0) ? 1 : 0;
    for (int e = 0; e < EE; e++) if (e != m1 && nz[e] > nz[m2]) m2 = e;
    float eb = expf(nz[m2] - nz[m1]);
    float den = 1.f + eb;
    float g1 = 1.f / den, g2 = eb / den;
    gating[(size_t)t * EE + m1] = g1;
    gating[(size_t)t * EE + m2] = g2;
    sel_e[t * 2] = m1; sel_e[t * 2 + 1] = m2;
    sel_g[t * 2] = g1; sel_g[t * 2 + 1] = g2;
  }
}

// ---------------- histogram + exclusive scan (1 block)
__global__ __launch_bounds__(256) void hist_scan_kernel(
    const int* __restrict__ sel_e, int* __restrict__ counts,
    int* __restrict__ offsets, int* __restrict__ cursors) {
  __shared__ int hist[EE];
  int tid = threadIdx.x;
  if (tid < EE) hist[tid] = 0;
  __syncthreads();
  for (int i = tid; i < NASG; i += 256) atomicAdd(&hist[sel_e[i]], 1);
  __syncthreads();
  if (tid == 0) {
    int off = 0;
    for (int e = 0; e < EE; e++) {
      counts[e] = hist[e]; offsets[e] = off; cursors[e] = off; off += hist[e];
    }
  }
}

// ---------------- build per-expert token lists
__global__ __launch_bounds__(256) void build_lists_kernel(
    const int* __restrict__ sel_e, const float* __restrict__ sel_g,
    int* __restrict__ cursors, int* __restrict__ tok_list,
    float* __restrict__ gate_list) {
  int t = blockIdx.x * 256 + threadIdx.x;
  int lane = threadIdx.x & 63;
#pragma unroll
  for (int k = 0; k < TOPK; k++) {
    int e = sel_e[t * 2 + k];
    float g = sel_g[t * 2 + k];
    for (int ee = 0; ee < EE; ee++) {
      unsigned long long m = __ballot(e == ee);
      if (m) {
        int leader = __ffsll(m) - 1;
        int base = 0;
        if (lane == leader) base = atomicAdd(&cursors[ee], __popcll(m));
        base = __shfl(base, leader);
        if (e == ee) {
          int slot = base + __popcll(m & ((1ull << lane) - 1ull));
          tok_list[slot] = t;
          gate_list[slot] = g;
        }
      }
    }
  }
}

// ---------------- zero-fill non-selected expert_out rows (gate == 0 exactly)
__global__ __launch_bounds__(256) void zerofill_kernel(
    const float* __restrict__ gating, float* __restrict__ expert_out) {
  int id = blockIdx.x;              // 0 .. EE*TKN-1
  int e = id >> 13, t = id & (TKN - 1);
  if (gating[(size_t)t * EE + e] != 0.f) return;
  float4* p = (float4*)(expert_out + ((size_t)e * TKN + t) * DD);
  p[threadIdx.x] = (float4){0.f, 0.f, 0.f, 0.f};
}

// ---------------- combine: final[t] = expert_out[e1][t] + expert_out[e2][t]
__global__ __launch_bounds__(256) void combine_kernel(
    const float* __restrict__ expert_out, const int* __restrict__ sel_e,
    float* __restrict__ final_out) {
  int t = blockIdx.x;
  int e1 = sel_e[2 * t], e2 = sel_e[2 * t + 1];
  const float4* r1 = (const float4*)(expert_out + ((size_t)e1 * TKN + t) * DD);
  const float4* r2 = (const float4*)(expert_out + ((size_t)e2 * TKN + t) * DD);
  float4* o = (float4*)(final_out + (size_t)t * DD);
  int i = threadIdx.x;
  float4 a = r1[i], b = r2[i];
  o[i] = (float4){a.x + b.x, a.y + b.y, a.z + b.z, a.w + b.w};
}

// ---------------- 256x256 / BK=32 / 8-wave grouped GEMM, 64KB LDS (2 blocks/CU)
// LDS row = 64B (32 bf16), 4 chunks of 16B. Stored chunk c holds global chunk
// c ^ ((row>>1)&3)  -> every wave b128 read is 2-way (free). Staging pre-applies
// the same involution on the per-lane GLOBAL address; LDS dest stays linear.
// Frag-read XOR reduces to the lane constant (fr>>1)&3 since frag rows = 16k+fr.
// vmcnt ledger (per-thread instrs, 2 per issue call):
//   entering tile t: B(t+1)[2] outstanding. P1 +A(t+1) -> 4. P3 +B(t+2) -> 6.
//   P4 vmcnt(2): completes B(t+1)+A(t+1) (needed by tile t+1), keeps B(t+2).
//   t = NT-2: P3 skipped (4 outstanding) -> vmcnt(0) drains A/B(NT-1).
template<int KLEN, bool GATHER, bool EPI2, bool REMAP>
__global__ __launch_bounds__(512, 4) void gemm8_kernel(
    const u16* __restrict__ A, const u16* __restrict__ Bm,
    const float* __restrict__ bias, const int* __restrict__ tok_list,
    const float* __restrict__ gate_list, const int* __restrict__ counts,
    const int* __restrict__ offsets, int Ncols,
    u16* __restrict__ OutBf, float* __restrict__ expert_out) {
  constexpr int NT = KLEN / 32;
  int e = blockIdx.z;
  int cnt = counts[e];
  int rt, ct;
  if (REMAP) {
    // XCD-friendly: the 4 col-tiles of one row-slice run on one XCD (ids = y'%8
    // + 8*x' + 32*(y'>>3); dispatch round-robin => same j%8 => same XCD).
    int j = blockIdx.y * gridDim.x + blockIdx.x;
    rt = (j & 7) + ((j >> 5) << 3);
    ct = (j >> 3) & 3;
  } else {
    rt = blockIdx.y; ct = blockIdx.x;
  }
  if (rt * 256 >= cnt) return;
  int off = offsets[e];
  int col0 = ct * 256;

  __shared__ __attribute__((aligned(16))) char ldsc[65536];  // A 32K | B 32K

  int tid = threadIdx.x;
  int w = tid >> 6, l = tid & 63;
  int wm = w >> 2, wn = w & 3;            // 2 x 4 wave grid
  int fr = l & 15, hi = l >> 4;
  int koff = ((hi ^ ((fr >> 1) & 3)) << 4);  // lane-constant frag chunk byte

  // staging: slot t covers (row = tid>>2 [+128], chunk = tid&3); global chunk
  // = (tid&3) ^ ((row>>1)&3) = (tid&3) ^ ((tid>>3)&3)  (row+128 same xor)
  int rowL0 = tid >> 2, rowL1 = rowL0 + 128;
  int gch = (tid & 3) ^ ((tid >> 3) & 3);
  const u16 *aptr0, *aptr1, *bptr0, *bptr1;
  {
    int r0 = rt * 256 + rowL0, r1 = rt * 256 + rowL1;
    if (GATHER) {
      aptr0 = A + (size_t)tok_list[min(off + r0, NASG - 1)] * KLEN + gch * 8;
      aptr1 = A + (size_t)tok_list[min(off + r1, NASG - 1)] * KLEN + gch * 8;
    } else {
      aptr0 = A + (size_t)(off + r0) * KLEN + gch * 8;
      aptr1 = A + (size_t)(off + r1) * KLEN + gch * 8;
    }
    bptr0 = Bm + ((size_t)e * Ncols + col0 + rowL0) * KLEN + gch * 8;
    bptr1 = Bm + ((size_t)e * Ncols + col0 + rowL1) * KLEN + gch * 8;
  }
  char* ldsA = ldsc;
  char* ldsB = ldsc + 32768;

  auto issueA = [&](int t) {
    char* d = ldsA + (t & 1) * 16384 + w * 1024;
    glds16(aptr0 + t * 32, d);
    glds16(aptr1 + t * 32, d + 8192);
  };
  auto issueB = [&](int t) {
    char* d = ldsB + (t & 1) * 16384 + w * 1024;
    glds16(bptr0 + t * 32, d);
    glds16(bptr1 + t * 32, d + 8192);
  };

  f32x4 acc[8][4];
#pragma unroll
  for (int m = 0; m < 8; m++)
#pragma unroll
    for (int n = 0; n < 4; n++) acc[m][n] = (f32x4){0.f, 0.f, 0.f, 0.f};
  bf16x8 aLo[4], aHi[4], bLo[2], bHi[2];

  // prologue
  issueA(0); issueB(0);
  issueB(1);            // NT >= 32 always
  VMCNT2();
  BAR();

  for (int t = 0; t < NT; t++) {
    int ab = (t & 1) * 16384;
    int bb = 32768 + (t & 1) * 16384;
    // ---- P1: read aLo + bLo; issue A(t+1)
#pragma unroll
    for (int mm = 0; mm < 4; mm++)
      aLo[mm] = *(const bf16x8*)(ldsc + ab + (wm * 128 + mm * 16 + fr) * 64 + koff);
#pragma unroll
    for (int nn = 0; nn < 2; nn++)
      bLo[nn] = *(const bf16x8*)(ldsc + bb + (wn * 64 + nn * 16 + fr) * 64 + koff);
    if (t + 1 < NT) issueA(t + 1);
    BAR();
    __builtin_amdgcn_s_setprio(1);
#pragma unroll
    for (int mm = 0; mm < 4; mm++)
#pragma unroll
      for (int nn = 0; nn < 2; nn++)
        acc[mm][nn] = __builtin_amdgcn_mfma_f32_16x16x32_bf16(aLo[mm], bLo[nn], acc[mm][nn], 0, 0, 0);
    __builtin_amdgcn_s_setprio(0);
    BAR();
    // ---- P2: read bHi
#pragma unroll
    for (int nn = 0; nn < 2; nn++)
      bHi[nn] = *(const bf16x8*)(ldsc + bb + (wn * 64 + 32 + nn * 16 + fr) * 64 + koff);
    BAR();
    __builtin_amdgcn_s_setprio(1);
#pragma unroll
    for (int mm = 0; mm < 4; mm++)
#pragma unroll
      for (int nn = 0; nn < 2; nn++)
        acc[mm][2 + nn] = __builtin_amdgcn_mfma_f32_16x16x32_bf16(aLo[mm], bHi[nn], acc[mm][2 + nn], 0, 0, 0);
    __builtin_amdgcn_s_setprio(0);
    BAR();
    // ---- P3: read aHi; issue B(t+2)
#pragma unroll
    for (int mm = 0; mm < 4; mm++)
      aHi[mm] = *(const bf16x8*)(ldsc + ab + (wm * 128 + 64 + mm * 16 + fr) * 64 + koff);
    if (t + 2 < NT) issueB(t + 2);
    BAR();
    __builtin_amdgcn_s_setprio(1);
#pragma unroll
    for (int mm = 0; mm < 4; mm++)
#pragma unroll
      for (int nn = 0; nn < 2; nn++)
        acc[4 + mm][nn] = __builtin_amdgcn_mfma_f32_16x16x32_bf16(aHi[mm], bLo[nn], acc[4 + mm][nn], 0, 0, 0);
    __builtin_amdgcn_s_setprio(0);
    BAR();
    // ---- P4: counted wait (steady) / drain (tail)
    if (t + 2 < NT) { VMCNT2(); } else { VMCNT0(); }
    BAR();
    __builtin_amdgcn_s_setprio(1);
#pragma unroll
    for (int mm = 0; mm < 4; mm++)
#pragma unroll
      for (int nn = 0; nn < 2; nn++)
        acc[4 + mm][2 + nn] = __builtin_amdgcn_mfma_f32_16x16x32_bf16(aHi[mm], bHi[nn], acc[4 + mm][2 + nn], 0, 0, 0);
    __builtin_amdgcn_s_setprio(0);
    BAR();
  }

  // ---- epilogue
  float biasN[4];
  int cN[4];
#pragma unroll
  for (int n = 0; n < 4; n++) {
    cN[n] = col0 + wn * 64 + (n >> 1) * 32 + (n & 1) * 16 + fr;
    biasN[n] = bias[e * Ncols + cN[n]];
  }
  if constexpr (!EPI2) {
#pragma unroll
    for (int m = 0; m < 8; m++) {
      int rb = rt * 256 + wm * 128 + (m >> 2) * 64 + (m & 3) * 16 + hi * 4;
#pragma unroll
      for (int j = 0; j < 4; j++) {
        int r = rb + j;
        if (r < cnt) {
#pragma unroll
          for (int n = 0; n < 4; n++) {
            float v = acc[m][n][j] + biasN[n];
            OutBf[(size_t)(off + r) * Ncols + cN[n]] = f2bf(fmaxf(v, 0.f));
          }
        }
      }
    }
  } else {
#pragma unroll
    for (int m = 0; m < 8; m++) {
      int rb = rt * 256 + wm * 128 + (m >> 2) * 64 + (m & 3) * 16 + hi * 4;
#pragma unroll
      for (int j = 0; j < 4; j++) {
        int r = rb + j;
        if (r < cnt) {
          int idx = off + r;
          int tok = tok_list[idx];
          float g = gate_list[idx];
          size_t erow = ((size_t)e * TKN + tok) * DD;
#pragma unroll
          for (int n = 0; n < 4; n++)
            expert_out[erow + cN[n]] = (acc[m][n][j] + biasN[n]) * g;
        }
      }
    }
  }
}

extern "C" void kernel_launch(void* const* d_in, const int* in_sizes, int n_in,
                              void* d_out, int out_size, void* d_ws, size_t ws_size,
                              hipStream_t stream) {
  const float* x     = (const float*)d_in[0];
  const float* noise = (const float*)d_in[1];
  const float* Wg    = (const float*)d_in[2];
  const float* bg    = (const float*)d_in[3];
  const float* Wn    = (const float*)d_in[4];
  const float* bn    = (const float*)d_in[5];
  const float* W1    = (const float*)d_in[6];
  const float* b1    = (const float*)d_in[7];
  const float* W2    = (const float*)d_in[8];
  const float* b2    = (const float*)d_in[9];

  float* final_out  = (float*)d_out;
  float* expert_out = final_out + (size_t)TKN * DD;
  float* gating     = expert_out + (size_t)EE * TKN * DD;

  char* ws = (char*)d_ws;
  size_t o = 0;
  auto alloc = [&](size_t bytes) {
    char* p = ws + o;
    o += bytes;
    o = (o + 255) & ~(size_t)255;
    return p;
  };
  u16*   xb        = (u16*)alloc((size_t)TKN * DD * 2);
  u16*   w1t       = (u16*)alloc((size_t)EE * HH * DD * 2);        // [E][H][D]
  u16*   w2t       = (u16*)alloc((size_t)EE * DD * HH * 2);        // [E][D][H]
  u16*   hbuf      = (u16*)alloc(((size_t)NASG + 256) * HH * 2);   // +256 pad rows
  int*   tok_list  = (int*)alloc((size_t)NASG * 4);
  float* gate_list = (float*)alloc((size_t)NASG * 4);
  int*   sel_e     = (int*)alloc((size_t)NASG * 4);
  float* sel_g     = (float*)alloc((size_t)NASG * 4);
  int*   counts    = (int*)alloc(256);
  int*   offsets   = (int*)alloc(256);
  int*   cursors   = (int*)alloc(256);

  // zero only gating (router writes just the top-2 entries per token)
  hipMemsetAsync(gating, 0, (size_t)TKN * EE * sizeof(float), stream);

  router_kernel<<<TKN, 256, 0, stream>>>(x, noise, Wg, bg, Wn, bn, gating, xb, sel_e, sel_g);
  hist_scan_kernel<<<1, 256, 0, stream>>>(sel_e, counts, offsets, cursors);
  build_lists_kernel<<<TKN / 256, 256, 0, stream>>>(sel_e, sel_g, cursors, tok_list, gate_list);
  // zero only the non-selected expert_out rows (selected rows are fully
  // overwritten by gemm2; gate==0 <=> not selected, incl. underflow case
  // where reference row is exactly 0 as well)
  zerofill_kernel<<<EE * TKN, 256, 0, stream>>>(gating, expert_out);

  transpose_cvt_kernel<<<dim3(HH / 32, DD / 32, EE), dim3(32, 8), 0, stream>>>(W1, w1t, DD, HH);
  transpose_cvt_kernel<<<dim3(DD / 32, HH / 32, EE), dim3(32, 8), 0, stream>>>(W2, w2t, HH, DD);

  // GEMM1: h = relu(x[tok] @ W1[e] + b1), K=1024, N=4096
  gemm8_kernel<DD, true, false, false><<<dim3(HH / 256, 32, EE), 512, 0, stream>>>(
      xb, w1t, b1, tok_list, nullptr, counts, offsets, HH, hbuf, nullptr);
  // GEMM2: y = (h @ W2[e] + b2) * gate -> expert_out, K=4096, N=1024
  gemm8_kernel<HH, false, true, true><<<dim3(DD / 256, 32, EE), 512, 0, stream>>>(
      hbuf, w2t, b2, tok_list, gate_list, counts, offsets, DD, nullptr, expert_out);

  // final[t] = sum of its two experts' rows (no atomics, no pre-zero)
  combine_kernel<<<TKN, 256, 0, stream>>>(expert_out, sel_e, final_out);
}

// Round 5
// 670.452 us; speedup vs baseline: 4.6429x; 4.6429x over previous
//
#include <hip/hip_runtime.h>
#include <hip/hip_bf16.h>
#include <stdint.h>

// Problem constants: B=8,S=1024,D=1024,E=8,H=4096,top_k=2
#define TKN   8192
#define DD    1024
#define EE    8
#define HH    4096
#define TOPK  2
#define NASG  (TKN * TOPK)      // 16384 assignments
#define NSLOT 72                // >= sum_e ceil(cnt_e/256) (<= 64+7)

typedef unsigned short u16;
typedef __bf16 bf16x8 __attribute__((ext_vector_type(8)));
typedef float  f32x4  __attribute__((ext_vector_type(4)));

__device__ __forceinline__ u16 f2bf(float f) {
  __hip_bfloat16 h = __float2bfloat16(f);
  return __builtin_bit_cast(u16, h);
}

__device__ __forceinline__ void glds16(const void* g, void* l) {
  __builtin_amdgcn_global_load_lds(
      (__attribute__((address_space(1))) void*)g,
      (__attribute__((address_space(3))) void*)l, 16, 0, 0);
}

#define FENCE() asm volatile("" ::: "memory")
#define BAR()   do { FENCE(); __builtin_amdgcn_s_barrier(); FENCE(); } while (0)
#define VMCNT8() asm volatile("s_waitcnt vmcnt(8)" ::: "memory")
#define VMCNT0() asm volatile("s_waitcnt vmcnt(0)" ::: "memory")

// ---------------- transpose + f32->bf16 convert: [E][R][C] f32 -> [E][C][R] bf16
__global__ __launch_bounds__(256) void transpose_cvt_kernel(
    const float* __restrict__ src, u16* __restrict__ dst, int R, int C) {
  __shared__ float tile[32][33];
  int e = blockIdx.z;
  int c0 = blockIdx.x * 32, r0 = blockIdx.y * 32;
  int tx = threadIdx.x, ty = threadIdx.y;  // 32 x 8
  const float* s = src + (size_t)e * R * C;
  u16* d = dst + (size_t)e * R * C;
#pragma unroll
  for (int j = 0; j < 4; j++)
    tile[ty * 4 + j][tx] = s[(size_t)(r0 + ty * 4 + j) * C + c0 + tx];
  __syncthreads();
#pragma unroll
  for (int j = 0; j < 4; j++)
    d[(size_t)(c0 + ty * 4 + j) * R + r0 + tx] = f2bf(tile[tx][ty * 4 + j]);
}

// ---------------- router
__global__ __launch_bounds__(256) void router_kernel(
    const float* __restrict__ x, const float* __restrict__ noise,
    const float* __restrict__ Wg, const float* __restrict__ bg,
    const float* __restrict__ Wn, const float* __restrict__ bn,
    float* __restrict__ gating, u16* __restrict__ xb,
    int* __restrict__ sel_e, float* __restrict__ sel_g) {
  int t = blockIdx.x;
  int tid = threadIdx.x;
  float acc[16];
#pragma unroll
  for (int j = 0; j < 16; j++) acc[j] = 0.f;
  for (int i = tid; i < DD; i += 256) {
    float xv = x[(size_t)t * DD + i];
    xb[(size_t)t * DD + i] = f2bf(xv);
    const float4* g4 = (const float4*)(Wg + (size_t)i * EE);
    const float4* n4 = (const float4*)(Wn + (size_t)i * EE);
    float4 ga = g4[0], gb = g4[1];
    float4 na = n4[0], nb = n4[1];
    acc[0] += xv * ga.x;  acc[1] += xv * ga.y;  acc[2] += xv * ga.z;  acc[3] += xv * ga.w;
    acc[4] += xv * gb.x;  acc[5] += xv * gb.y;  acc[6] += xv * gb.z;  acc[7] += xv * gb.w;
    acc[8] += xv * na.x;  acc[9] += xv * na.y;  acc[10] += xv * na.z; acc[11] += xv * na.w;
    acc[12] += xv * nb.x; acc[13] += xv * nb.y; acc[14] += xv * nb.z; acc[15] += xv * nb.w;
  }
  __shared__ float red[4][16];
  int lane = tid & 63, wv = tid >> 6;
#pragma unroll
  for (int j = 0; j < 16; j++) {
    float v = acc[j];
    for (int o = 32; o > 0; o >>= 1) v += __shfl_down(v, o);
    acc[j] = v;
  }
  if (lane == 0) {
#pragma unroll
    for (int j = 0; j < 16; j++) red[wv][j] = acc[j];
  }
  __syncthreads();
  if (tid == 0) {
    float nz[EE];
#pragma unroll
    for (int e = 0; e < EE; e++) {
      float dg = red[0][e] + red[1][e] + red[2][e] + red[3][e] + bg[e];
      float dn = red[0][8 + e] + red[1][8 + e] + red[2][8 + e] + red[3][8 + e] + bn[e];
      float sp = fmaxf(dn, 0.f) + log1pf(expf(-fabsf(dn)));
      nz[e] = dg + noise[(size_t)t * EE + e] * sp;
    }
    int m1 = 0;
    for (int e = 1; e < EE; e++) if (nz[e] > nz[m1]) m1 = e;
    int m2 = (m1 == 0) ? 1 : 0;
    for (int e = 0; e < EE; e++) if (e != m1 && nz[e] > nz[m2]) m2 = e;
    float eb = expf(nz[m2] - nz[m1]);
    float den = 1.f + eb;
    float g1 = 1.f / den, g2 = eb / den;
    gating[(size_t)t * EE + m1] = g1;
    gating[(size_t)t * EE + m2] = g2;
    sel_e[t * 2] = m1; sel_e[t * 2 + 1] = m2;
    sel_g[t * 2] = g1; sel_g[t * 2 + 1] = g2;
  }
}

// ---------------- histogram + scan + slot table (1 block)
__global__ __launch_bounds__(256) void hist_scan_kernel(
    const int* __restrict__ sel_e, int* __restrict__ counts,
    int* __restrict__ offsets, int* __restrict__ cursors,
    int* __restrict__ slots) {
  __shared__ int hist[EE];
  int tid = threadIdx.x;
  if (tid < EE) hist[tid] = 0;
  __syncthreads();
  for (int i = tid; i < NASG; i += 256) atomicAdd(&hist[sel_e[i]], 1);
  __syncthreads();
  if (tid == 0) {
    int off = 0, ns = 0;
    for (int e = 0; e < EE; e++) {
      int c = hist[e];
      counts[e] = c; offsets[e] = off; cursors[e] = off; off += c;
      int nrt = (c + 255) >> 8;
      for (int rt = 0; rt < nrt; rt++) slots[ns++] = (e << 16) | rt;
    }
    for (; ns < NSLOT; ns++) slots[ns] = -1;
  }
}

// ---------------- build per-expert token lists
__global__ __launch_bounds__(256) void build_lists_kernel(
    const int* __restrict__ sel_e, const float* __restrict__ sel_g,
    int* __restrict__ cursors, int* __restrict__ tok_list,
    float* __restrict__ gate_list) {
  int t = blockIdx.x * 256 + threadIdx.x;
  int lane = threadIdx.x & 63;
#pragma unroll
  for (int k = 0; k < TOPK; k++) {
    int e = sel_e[t * 2 + k];
    float g = sel_g[t * 2 + k];
    for (int ee = 0; ee < EE; ee++) {
      unsigned long long m = __ballot(e == ee);
      if (m) {
        int leader = __ffsll(m) - 1;
        int base = 0;
        if (lane == leader) base = atomicAdd(&cursors[ee], __popcll(m));
        base = __shfl(base, leader);
        if (e == ee) {
          int slot = base + __popcll(m & ((1ull << lane) - 1ull));
          tok_list[slot] = t;
          gate_list[slot] = g;
        }
      }
    }
  }
}

// ---------------- zero-fill non-selected expert_out rows (gate == 0 exactly)
__global__ __launch_bounds__(256) void zerofill_kernel(
    const float* __restrict__ gating, float* __restrict__ expert_out) {
  int id = blockIdx.x;              // 0 .. EE*TKN-1
  int e = id >> 13, t = id & (TKN - 1);
  if (gating[(size_t)t * EE + e] != 0.f) return;
  float4* p = (float4*)(expert_out + ((size_t)e * TKN + t) * DD);
  p[threadIdx.x] = (float4){0.f, 0.f, 0.f, 0.f};
}

// ---------------- combine: final[t] = expert_out[e1][t] + expert_out[e2][t]
__global__ __launch_bounds__(256) void combine_kernel(
    const float* __restrict__ expert_out, const int* __restrict__ sel_e,
    float* __restrict__ final_out) {
  int t = blockIdx.x;
  int e1 = sel_e[2 * t], e2 = sel_e[2 * t + 1];
  const float4* r1 = (const float4*)(expert_out + ((size_t)e1 * TKN + t) * DD);
  const float4* r2 = (const float4*)(expert_out + ((size_t)e2 * TKN + t) * DD);
  float4* o = (float4*)(final_out + (size_t)t * DD);
  int i = threadIdx.x;
  float4 a = r1[i], b = r2[i];
  o[i] = (float4){a.x + b.x, a.y + b.y, a.z + b.z, a.w + b.w};
}

// ---------------- 256x256 / BK=64 / 8-wave grouped GEMM (round-3 core)
// Slot-compact 1-D grid: gid -> xcd=gid&7, q=gid>>3, slot=xcd*9+(q>>LOGC),
// ct=q&((1<<LOGC)-1). All col-tiles of a slot land on one XCD consecutively
// (A-slice fetched once per XCD); dead slots (-1) exit immediately.
// LDS swizzle: stored 16B chunk c of row r holds global chunk c^(r&7) —
// linear global_load_lds dest + inverse-swizzled per-lane global source.
// Prefetch: B(t+2) issued in P3, A(t+2) in P4 (safe: that buffer's LDS reads
// complete before the preceding MFMA-barrier via compiler lgkmcnt).
// vmcnt ledger (2 loads per issue call, 4 per A/B tile):
//   P4 of tile t: outstanding B(t+1)4 A(t+1)4 B(t+2)4 A(t+2)4 = 16
//   -> vmcnt(8) completes B(t+1)+A(t+1) (each issued 4-5 phases ago).
//   t = NT-2: nothing issued, 8 outstanding -> vmcnt(0) drains A/B(NT-1).
template<int KLEN, bool GATHER, bool EPI2, int LOGC>
__global__ __launch_bounds__(512, 2) void gemm8_kernel(
    const u16* __restrict__ A, const u16* __restrict__ Bm,
    const float* __restrict__ bias, const int* __restrict__ tok_list,
    const float* __restrict__ gate_list, const int* __restrict__ counts,
    const int* __restrict__ offsets, const int* __restrict__ slots,
    int Ncols, u16* __restrict__ OutBf, float* __restrict__ expert_out) {
  constexpr int NT = KLEN / 64;
  int gid = blockIdx.x;
  int q = gid >> 3;
  int slot = (gid & 7) * 9 + (q >> LOGC);
  int ct = q & ((1 << LOGC) - 1);
  int packed = slots[slot];
  if (packed < 0) return;
  int e = packed >> 16;
  int rt = packed & 0xffff;
  int cnt = counts[e];
  int off = offsets[e];
  int col0 = ct * 256;

  __shared__ __attribute__((aligned(16))) char ldsc[131072];  // A 64K | B 64K

  int tid = threadIdx.x;
  int w = tid >> 6, l = tid & 63;
  int wm = w >> 2, wn = w & 3;            // 2 x 4 wave grid
  int fr = l & 15, hi = l >> 4;
  int kk16 = hi << 4;
  int xr = (fr & 7) << 4;

  int rl0 = w * 8 + (l >> 3);
  int slotE = ((l & 7) ^ ((l >> 3) & 7)) << 3;  // pre-swizzled 8-elem slot
  const u16* aptr[4];
  const u16* bptr[4];
#pragma unroll
  for (int i = 0; i < 4; i++) {
    int r = rt * 256 + rl0 + i * 64;
    if (GATHER) {
      int idx = min(off + r, NASG - 1);
      aptr[i] = A + (size_t)tok_list[idx] * KLEN + slotE;
    } else {
      aptr[i] = A + (size_t)(off + r) * KLEN + slotE;
    }
    bptr[i] = Bm + ((size_t)e * Ncols + col0 + rl0 + i * 64) * KLEN + slotE;
  }
  char* ldsA = ldsc;
  char* ldsB = ldsc + 65536;

  auto issueA = [&](int t, int h) {
    char* d = ldsA + (t & 1) * 32768 + h * 16384 + w * 1024;
    glds16(aptr[h * 2 + 0] + t * 64, d);
    glds16(aptr[h * 2 + 1] + t * 64, d + 8192);
  };
  auto issueB = [&](int t, int h) {
    char* d = ldsB + (t & 1) * 32768 + h * 16384 + w * 1024;
    glds16(bptr[h * 2 + 0] + t * 64, d);
    glds16(bptr[h * 2 + 1] + t * 64, d + 8192);
  };

  f32x4 acc[8][4];
#pragma unroll
  for (int m = 0; m < 8; m++)
#pragma unroll
    for (int n = 0; n < 4; n++) acc[m][n] = (f32x4){0.f, 0.f, 0.f, 0.f};
  bf16x8 aF[4][2], bF0[2][2], bF1[2][2];

  // prologue: B0 A0 B1 A1 (16 loads); vmcnt(8) -> B0,A0 complete
  issueB(0, 0); issueB(0, 1); issueA(0, 0); issueA(0, 1);
  issueB(1, 0); issueB(1, 1); issueA(1, 0); issueA(1, 1);
  VMCNT8();
  BAR();

  for (int t = 0; t < NT; t++) {
    int abase = (t & 1) * 32768;
    int bbase = 65536 + (t & 1) * 32768;
    // ---- P1: read A(mh0)+B(nh0)
#pragma unroll
    for (int mm = 0; mm < 4; mm++)
#pragma unroll
      for (int ks = 0; ks < 2; ks++)
        aF[mm][ks] = *(const bf16x8*)(ldsc + abase + (wm * 128 + mm * 16 + fr) * 128 +
                                      ((ks * 64 + kk16) ^ xr));
#pragma unroll
    for (int nn = 0; nn < 2; nn++)
#pragma unroll
      for (int ks = 0; ks < 2; ks++)
        bF0[nn][ks] = *(const bf16x8*)(ldsc + bbase + (wn * 64 + nn * 16 + fr) * 128 +
                                       ((ks * 64 + kk16) ^ xr));
    BAR();
    __builtin_amdgcn_s_setprio(1);
#pragma unroll
    for (int mm = 0; mm < 4; mm++)
#pragma unroll
      for (int nn = 0; nn < 2; nn++)
#pragma unroll
        for (int ks = 0; ks < 2; ks++)
          acc[mm][nn] = __builtin_amdgcn_mfma_f32_16x16x32_bf16(aF[mm][ks], bF0[nn][ks], acc[mm][nn], 0, 0, 0);
    __builtin_amdgcn_s_setprio(0);
    BAR();
    // ---- P2: read B(nh1)
#pragma unroll
    for (int nn = 0; nn < 2; nn++)
#pragma unroll
      for (int ks = 0; ks < 2; ks++)
        bF1[nn][ks] = *(const bf16x8*)(ldsc + bbase + (wn * 64 + 32 + nn * 16 + fr) * 128 +
                                       ((ks * 64 + kk16) ^ xr));
    BAR();
    __builtin_amdgcn_s_setprio(1);
#pragma unroll
    for (int mm = 0; mm < 4; mm++)
#pragma unroll
      for (int nn = 0; nn < 2; nn++)
#pragma unroll
        for (int ks = 0; ks < 2; ks++)
          acc[mm][2 + nn] = __builtin_amdgcn_mfma_f32_16x16x32_bf16(aF[mm][ks], bF1[nn][ks], acc[mm][2 + nn], 0, 0, 0);
    __builtin_amdgcn_s_setprio(0);
    BAR();
    // ---- P3: read A(mh1); issue B(t+2) (B buffer t&1: all its ds_reads
    // completed before P2's MFMA barrier)
#pragma unroll
    for (int mm = 0; mm < 4; mm++)
#pragma unroll
      for (int ks = 0; ks < 2; ks++)
        aF[mm][ks] = *(const bf16x8*)(ldsc + abase + (wm * 128 + 64 + mm * 16 + fr) * 128 +
                                      ((ks * 64 + kk16) ^ xr));
    if (t + 2 < NT) { issueB(t + 2, 0); issueB(t + 2, 1); }
    BAR();
    __builtin_amdgcn_s_setprio(1);
#pragma unroll
    for (int mm = 0; mm < 4; mm++)
#pragma unroll
      for (int nn = 0; nn < 2; nn++)
#pragma unroll
        for (int ks = 0; ks < 2; ks++)
          acc[4 + mm][nn] = __builtin_amdgcn_mfma_f32_16x16x32_bf16(aF[mm][ks], bF0[nn][ks], acc[4 + mm][nn], 0, 0, 0);
    __builtin_amdgcn_s_setprio(0);
    BAR();
    // ---- P4: issue A(t+2) (A buffer t&1 reads done before P3's MFMA
    // barrier); counted wait steady / drain at tail
    if (t + 2 < NT) {
      issueA(t + 2, 0); issueA(t + 2, 1);
      VMCNT8();
    } else {
      VMCNT0();
    }
    BAR();
    __builtin_amdgcn_s_setprio(1);
#pragma unroll
    for (int mm = 0; mm < 4; mm++)
#pragma unroll
      for (int nn = 0; nn < 2; nn++)
#pragma unroll
        for (int ks = 0; ks < 2; ks++)
          acc[4 + mm][2 + nn] = __builtin_amdgcn_mfma_f32_16x16x32_bf16(aF[mm][ks], bF1[nn][ks], acc[4 + mm][2 + nn], 0, 0, 0);
    __builtin_amdgcn_s_setprio(0);
    BAR();
  }

  // ---- epilogue
  float biasN[4];
  int cN[4];
#pragma unroll
  for (int n = 0; n < 4; n++) {
    cN[n] = col0 + wn * 64 + (n >> 1) * 32 + (n & 1) * 16 + fr;
    biasN[n] = bias[e * Ncols + cN[n]];
  }
  if constexpr (!EPI2) {
#pragma unroll
    for (int m = 0; m < 8; m++) {
      int rb = rt * 256 + wm * 128 + (m >> 2) * 64 + (m & 3) * 16 + hi * 4;
#pragma unroll
      for (int j = 0; j < 4; j++) {
        int r = rb + j;
        if (r < cnt) {
#pragma unroll
          for (int n = 0; n < 4; n++) {
            float v = acc[m][n][j] + biasN[n];
            OutBf[(size_t)(off + r) * Ncols + cN[n]] = f2bf(fmaxf(v, 0.f));
          }
        }
      }
    }
  } else {
#pragma unroll
    for (int m = 0; m < 8; m++) {
      int rb = rt * 256 + wm * 128 + (m >> 2) * 64 + (m & 3) * 16 + hi * 4;
#pragma unroll
      for (int j = 0; j < 4; j++) {
        int r = rb + j;
        if (r < cnt) {
          int idx = off + r;
          int tok = tok_list[idx];
          float g = gate_list[idx];
          size_t erow = ((size_t)e * TKN + tok) * DD;
#pragma unroll
          for (int n = 0; n < 4; n++)
            expert_out[erow + cN[n]] = (acc[m][n][j] + biasN[n]) * g;
        }
      }
    }
  }
}

extern "C" void kernel_launch(void* const* d_in, const int* in_sizes, int n_in,
                              void* d_out, int out_size, void* d_ws, size_t ws_size,
                              hipStream_t stream) {
  const float* x     = (const float*)d_in[0];
  const float* noise = (const float*)d_in[1];
  const float* Wg    = (const float*)d_in[2];
  const float* bg    = (const float*)d_in[3];
  const float* Wn    = (const float*)d_in[4];
  const float* bn    = (const float*)d_in[5];
  const float* W1    = (const float*)d_in[6];
  const float* b1    = (const float*)d_in[7];
  const float* W2    = (const float*)d_in[8];
  const float* b2    = (const float*)d_in[9];

  float* final_out  = (float*)d_out;
  float* expert_out = final_out + (size_t)TKN * DD;
  float* gating     = expert_out + (size_t)EE * TKN * DD;

  char* ws = (char*)d_ws;
  size_t o = 0;
  auto alloc = [&](size_t bytes) {
    char* p = ws + o;
    o += bytes;
    o = (o + 255) & ~(size_t)255;
    return p;
  };
  u16*   xb        = (u16*)alloc((size_t)TKN * DD * 2);
  u16*   w1t       = (u16*)alloc((size_t)EE * HH * DD * 2);        // [E][H][D]
  u16*   w2t       = (u16*)alloc((size_t)EE * DD * HH * 2);        // [E][D][H]
  u16*   hbuf      = (u16*)alloc(((size_t)NASG + 256) * HH * 2);   // +256 pad rows
  int*   tok_list  = (int*)alloc((size_t)NASG * 4);
  float* gate_list = (float*)alloc((size_t)NASG * 4);
  int*   sel_e     = (int*)alloc((size_t)NASG * 4);
  float* sel_g     = (float*)alloc((size_t)NASG * 4);
  int*   counts    = (int*)alloc(256);
  int*   offsets   = (int*)alloc(256);
  int*   cursors   = (int*)alloc(256);
  int*   slots     = (int*)alloc(NSLOT * 4);

  // zero only gating (router writes just the top-2 entries per token)
  hipMemsetAsync(gating, 0, (size_t)TKN * EE * sizeof(float), stream);

  router_kernel<<<TKN, 256, 0, stream>>>(x, noise, Wg, bg, Wn, bn, gating, xb, sel_e, sel_g);
  hist_scan_kernel<<<1, 256, 0, stream>>>(sel_e, counts, offsets, cursors, slots);
  build_lists_kernel<<<TKN / 256, 256, 0, stream>>>(sel_e, sel_g, cursors, tok_list, gate_list);
  // zero only the non-selected expert_out rows (gate==0 <=> not selected)
  zerofill_kernel<<<EE * TKN, 256, 0, stream>>>(gating, expert_out);

  transpose_cvt_kernel<<<dim3(HH / 32, DD / 32, EE), dim3(32, 8), 0, stream>>>(W1, w1t, DD, HH);
  transpose_cvt_kernel<<<dim3(DD / 32, HH / 32, EE), dim3(32, 8), 0, stream>>>(W2, w2t, HH, DD);

  // GEMM1: h = relu(x[tok] @ W1[e] + b1), K=1024, N=4096; 16 col-tiles
  gemm8_kernel<DD, true, false, 4><<<8 * 9 * 16, 512, 0, stream>>>(
      xb, w1t, b1, tok_list, nullptr, counts, offsets, slots, HH, hbuf, nullptr);
  // GEMM2: y = (h @ W2[e] + b2) * gate -> expert_out, K=4096, N=1024; 4 col-tiles
  gemm8_kernel<HH, false, true, 2><<<8 * 9 * 4, 512, 0, stream>>>(
      hbuf, w2t, b2, tok_list, gate_list, counts, offsets, slots, DD, nullptr, expert_out);

  // final[t] = sum of its two experts' rows (no atomics, no pre-zero)
  combine_kernel<<<TKN, 256, 0, stream>>>(expert_out, sel_e, final_out);
}

// Round 6
// 668.124 us; speedup vs baseline: 4.6591x; 1.0035x over previous
//
#include <hip/hip_runtime.h>
#include <hip/hip_bf16.h>
#include <stdint.h>

// Problem constants: B=8,S=1024,D=1024,E=8,H=4096,top_k=2
#define TKN   8192
#define DD    1024
#define EE    8
#define HH    4096
#define TOPK  2
#define NASG  (TKN * TOPK)      // 16384 assignments
#define NSLOT 72                // >= sum_e ceil(cnt_e/256) (<= 64+7)

typedef unsigned short u16;
typedef __bf16 bf16x8 __attribute__((ext_vector_type(8)));
typedef float  f32x4  __attribute__((ext_vector_type(4)));

__device__ __forceinline__ u16 f2bf(float f) {
  __hip_bfloat16 h = __float2bfloat16(f);
  return __builtin_bit_cast(u16, h);
}

__device__ __forceinline__ void glds16(const void* g, void* l) {
  __builtin_amdgcn_global_load_lds(
      (__attribute__((address_space(1))) void*)g,
      (__attribute__((address_space(3))) void*)l, 16, 0, 0);
}

#define FENCE() asm volatile("" ::: "memory")
#define BAR()   do { FENCE(); __builtin_amdgcn_s_barrier(); FENCE(); } while (0)
#define VMCNT8() asm volatile("s_waitcnt vmcnt(8)" ::: "memory")
#define VMCNT0() asm volatile("s_waitcnt vmcnt(0)" ::: "memory")

// ---------------- transpose + f32->bf16: [E][R][C] f32 -> [E][C][R] bf16
// 64r x 32c tile; packed u32 stores (2 bf16) for full-width writes.
__global__ __launch_bounds__(256) void transpose_cvt_kernel(
    const float* __restrict__ src, u16* __restrict__ dst, int R, int C) {
  __shared__ float tile[64][33];
  int e = blockIdx.z;
  int c0 = blockIdx.x * 32, r0 = blockIdx.y * 64;
  int tx = threadIdx.x, ty = threadIdx.y;  // 32 x 8
  const float* s = src + (size_t)e * R * C;
  uint32_t* d32 = (uint32_t*)(dst + (size_t)e * R * C);
#pragma unroll
  for (int j = 0; j < 8; j++)
    tile[ty * 8 + j][tx] = s[(size_t)(r0 + ty * 8 + j) * C + c0 + tx];
  __syncthreads();
#pragma unroll
  for (int jj = 0; jj < 4; jj++) {
    int c = c0 + ty * 4 + jj;
    uint32_t lo = f2bf(tile[2 * tx][ty * 4 + jj]);
    uint32_t hi = f2bf(tile[2 * tx + 1][ty * 4 + jj]);
    d32[((size_t)c * R + r0) / 2 + tx] = lo | (hi << 16);
  }
}

// ---------------- router
__global__ __launch_bounds__(256) void router_kernel(
    const float* __restrict__ x, const float* __restrict__ noise,
    const float* __restrict__ Wg, const float* __restrict__ bg,
    const float* __restrict__ Wn, const float* __restrict__ bn,
    float* __restrict__ gating, u16* __restrict__ xb,
    int* __restrict__ sel_e, float* __restrict__ sel_g) {
  int t = blockIdx.x;
  int tid = threadIdx.x;
  float acc[16];
#pragma unroll
  for (int j = 0; j < 16; j++) acc[j] = 0.f;
  for (int i = tid; i < DD; i += 256) {
    float xv = x[(size_t)t * DD + i];
    xb[(size_t)t * DD + i] = f2bf(xv);
    const float4* g4 = (const float4*)(Wg + (size_t)i * EE);
    const float4* n4 = (const float4*)(Wn + (size_t)i * EE);
    float4 ga = g4[0], gb = g4[1];
    float4 na = n4[0], nb = n4[1];
    acc[0] += xv * ga.x;  acc[1] += xv * ga.y;  acc[2] += xv * ga.z;  acc[3] += xv * ga.w;
    acc[4] += xv * gb.x;  acc[5] += xv * gb.y;  acc[6] += xv * gb.z;  acc[7] += xv * gb.w;
    acc[8] += xv * na.x;  acc[9] += xv * na.y;  acc[10] += xv * na.z; acc[11] += xv * na.w;
    acc[12] += xv * nb.x; acc[13] += xv * nb.y; acc[14] += xv * nb.z; acc[15] += xv * nb.w;
  }
  __shared__ float red[4][16];
  int lane = tid & 63, wv = tid >> 6;
#pragma unroll
  for (int j = 0; j < 16; j++) {
    float v = acc[j];
    for (int o = 32; o > 0; o >>= 1) v += __shfl_down(v, o);
    acc[j] = v;
  }
  if (lane == 0) {
#pragma unroll
    for (int j = 0; j < 16; j++) red[wv][j] = acc[j];
  }
  __syncthreads();
  if (tid == 0) {
    float nz[EE];
#pragma unroll
    for (int e = 0; e < EE; e++) {
      float dg = red[0][e] + red[1][e] + red[2][e] + red[3][e] + bg[e];
      float dn = red[0][8 + e] + red[1][8 + e] + red[2][8 + e] + red[3][8 + e] + bn[e];
      float sp = fmaxf(dn, 0.f) + log1pf(expf(-fabsf(dn)));
      nz[e] = dg + noise[(size_t)t * EE + e] * sp;
    }
    int m1 = 0;
    for (int e = 1; e < EE; e++) if (nz[e] > nz[m1]) m1 = e;
    int m2 = (m1 == 0) ? 1 : 0;
    for (int e = 0; e < EE; e++) if (e != m1 && nz[e] > nz[m2]) m2 = e;
    float eb = expf(nz[m2] - nz[m1]);
    float den = 1.f + eb;
    float g1 = 1.f / den, g2 = eb / den;
    gating[(size_t)t * EE + m1] = g1;
    gating[(size_t)t * EE + m2] = g2;
    sel_e[t * 2] = m1; sel_e[t * 2 + 1] = m2;
    sel_g[t * 2] = g1; sel_g[t * 2 + 1] = g2;
  }
}

// ---------------- histogram + scan + slot table (1 block)
__global__ __launch_bounds__(256) void hist_scan_kernel(
    const int* __restrict__ sel_e, int* __restrict__ counts,
    int* __restrict__ offsets, int* __restrict__ cursors,
    int* __restrict__ slots) {
  __shared__ int hist[EE];
  int tid = threadIdx.x;
  if (tid < EE) hist[tid] = 0;
  __syncthreads();
  for (int i = tid; i < NASG; i += 256) atomicAdd(&hist[sel_e[i]], 1);
  __syncthreads();
  if (tid == 0) {
    int off = 0, ns = 0;
    for (int e = 0; e < EE; e++) {
      int c = hist[e];
      counts[e] = c; offsets[e] = off; cursors[e] = off; off += c;
      int nrt = (c + 255) >> 8;
      for (int rt = 0; rt < nrt; rt++) slots[ns++] = (e << 16) | rt;
    }
    for (; ns < NSLOT; ns++) slots[ns] = -1;
  }
}

// ---------------- build per-expert token lists (+ token->assignment-slot map)
__global__ __launch_bounds__(256) void build_lists_kernel(
    const int* __restrict__ sel_e, const float* __restrict__ sel_g,
    int* __restrict__ cursors, int* __restrict__ tok_list,
    float* __restrict__ gate_list, int* __restrict__ asg_of) {
  int t = blockIdx.x * 256 + threadIdx.x;
  int lane = threadIdx.x & 63;
#pragma unroll
  for (int k = 0; k < TOPK; k++) {
    int e = sel_e[t * 2 + k];
    float g = sel_g[t * 2 + k];
    for (int ee = 0; ee < EE; ee++) {
      unsigned long long m = __ballot(e == ee);
      if (m) {
        int leader = __ffsll(m) - 1;
        int base = 0;
        if (lane == leader) base = atomicAdd(&cursors[ee], __popcll(m));
        base = __shfl(base, leader);
        if (e == ee) {
          int slot = base + __popcll(m & ((1ull << lane) - 1ull));
          tok_list[slot] = t;
          gate_list[slot] = g;
          asg_of[t * 2 + k] = slot;
        }
      }
    }
  }
}

// ---------------- zero-fill non-selected expert_out rows (gate == 0 exactly)
__global__ __launch_bounds__(256) void zerofill_kernel(
    const float* __restrict__ gating, float* __restrict__ expert_out) {
  int id = blockIdx.x;              // 0 .. EE*TKN-1
  int e = id >> 13, t = id & (TKN - 1);
  if (gating[(size_t)t * EE + e] != 0.f) return;
  float4* p = (float4*)(expert_out + ((size_t)e * TKN + t) * DD);
  p[threadIdx.x] = (float4){0.f, 0.f, 0.f, 0.f};
}

// ---------------- combine (fallback path): final = expert rows sum
__global__ __launch_bounds__(256) void combine_kernel(
    const float* __restrict__ expert_out, const int* __restrict__ sel_e,
    float* __restrict__ final_out) {
  int t = blockIdx.x;
  int e1 = sel_e[2 * t], e2 = sel_e[2 * t + 1];
  const float4* r1 = (const float4*)(expert_out + ((size_t)e1 * TKN + t) * DD);
  const float4* r2 = (const float4*)(expert_out + ((size_t)e2 * TKN + t) * DD);
  float4* o = (float4*)(final_out + (size_t)t * DD);
  int i = threadIdx.x;
  float4 a = r1[i], b = r2[i];
  o[i] = (float4){a.x + b.x, a.y + b.y, a.z + b.z, a.w + b.w};
}

// ---------------- merge 4 K-partials + bias + gate -> expert rows + final
__global__ __launch_bounds__(256) void merge_combine_kernel(
    const float* __restrict__ part, const int* __restrict__ asg_of,
    const int* __restrict__ sel_e, const float* __restrict__ sel_g,
    const float* __restrict__ b2, float* __restrict__ expert_out,
    float* __restrict__ final_out) {
  int t = blockIdx.x;
  int i = threadIdx.x;
  int i1 = asg_of[2 * t], i2 = asg_of[2 * t + 1];
  int e1 = sel_e[2 * t], e2 = sel_e[2 * t + 1];
  float g1 = sel_g[2 * t], g2 = sel_g[2 * t + 1];
  float4 s1 = {0.f, 0.f, 0.f, 0.f}, s2 = {0.f, 0.f, 0.f, 0.f};
#pragma unroll
  for (int kq = 0; kq < 4; kq++) {
    float4 a = ((const float4*)(part + ((size_t)kq * NASG + i1) * DD))[i];
    float4 b = ((const float4*)(part + ((size_t)kq * NASG + i2) * DD))[i];
    s1.x += a.x; s1.y += a.y; s1.z += a.z; s1.w += a.w;
    s2.x += b.x; s2.y += b.y; s2.z += b.z; s2.w += b.w;
  }
  float4 bb1 = ((const float4*)(b2 + (size_t)e1 * DD))[i];
  float4 bb2 = ((const float4*)(b2 + (size_t)e2 * DD))[i];
  float4 y1 = {(s1.x + bb1.x) * g1, (s1.y + bb1.y) * g1, (s1.z + bb1.z) * g1, (s1.w + bb1.w) * g1};
  float4 y2 = {(s2.x + bb2.x) * g2, (s2.y + bb2.y) * g2, (s2.z + bb2.z) * g2, (s2.w + bb2.w) * g2};
  ((float4*)(expert_out + ((size_t)e1 * TKN + t) * DD))[i] = y1;
  ((float4*)(expert_out + ((size_t)e2 * TKN + t) * DD))[i] = y2;
  ((float4*)(final_out + (size_t)t * DD))[i] =
      (float4){y1.x + y2.x, y1.y + y2.y, y1.z + y2.z, y1.w + y2.w};
}

// ---------------- 256x256 / BK=64 / 8-wave grouped GEMM (round-3 core)
// EPI: 0 = relu->bf16 OutBf; 1 = (acc+bias)*gate -> expert_out; 2 = raw f32
// K-partial -> outF[kq][asg][DD].
// Decode (1-D grid, kq-outer within XCD): gid -> xcd=gid&7, q=gid>>3,
// kq=q/(9<<LOGC), r=q%(9<<LOGC), slot=xcd*9+(r>>LOGC), ct=r&mask.
// 32 consecutive gid on one XCD = 8 slots x 4 ct of one kq -> B-quarter tiles
// L2-reused by 8 slots, A-slices by 4 cts.
// vmcnt ledger: P3 issues B(t+2), P4 issues A(t+2); at P4 16 outstanding ->
// vmcnt(8) completes B(t+1)+A(t+1). Tail t>=NT-2: vmcnt(0) full drain.
template<int KLOOP, int KSTRIDE, bool GATHER, int EPI, int LOGC, int LOGK>
__global__ __launch_bounds__(512, 2) void gemm8_kernel(
    const u16* __restrict__ A, const u16* __restrict__ Bm,
    const float* __restrict__ bias, const int* __restrict__ tok_list,
    const float* __restrict__ gate_list, const int* __restrict__ counts,
    const int* __restrict__ offsets, const int* __restrict__ slots,
    int Ncols, u16* __restrict__ OutBf, float* __restrict__ outF) {
  constexpr int NT = KLOOP / 64;
  int gid = blockIdx.x;
  int q = gid >> 3;
  constexpr int PERX = 9 << LOGC;
  int kq = q / PERX;
  int r0q = q - kq * PERX;
  int slot = (gid & 7) * 9 + (r0q >> LOGC);
  int ct = r0q & ((1 << LOGC) - 1);
  int packed = slots[slot];
  if (packed < 0) return;
  int e = packed >> 16;
  int rt = packed & 0xffff;
  int cnt = counts[e];
  int off = offsets[e];
  int col0 = ct * 256;
  int k0e = kq * KLOOP;   // element offset of this K-slice

  __shared__ __attribute__((aligned(16))) char ldsc[131072];  // A 64K | B 64K

  int tid = threadIdx.x;
  int w = tid >> 6, l = tid & 63;
  int wm = w >> 2, wn = w & 3;            // 2 x 4 wave grid
  int fr = l & 15, hi = l >> 4;
  int kk16 = hi << 4;
  int xr = (fr & 7) << 4;

  int rl0 = w * 8 + (l >> 3);
  int slotE = ((l & 7) ^ ((l >> 3) & 7)) << 3;  // pre-swizzled 8-elem slot
  const u16* aptr[4];
  const u16* bptr[4];
#pragma unroll
  for (int i = 0; i < 4; i++) {
    int r = rt * 256 + rl0 + i * 64;
    if (GATHER) {
      int idx = min(off + r, NASG - 1);
      aptr[i] = A + (size_t)tok_list[idx] * KSTRIDE + k0e + slotE;
    } else {
      aptr[i] = A + (size_t)(off + r) * KSTRIDE + k0e + slotE;
    }
    bptr[i] = Bm + ((size_t)e * Ncols + col0 + rl0 + i * 64) * KSTRIDE + k0e + slotE;
  }
  char* ldsA = ldsc;
  char* ldsB = ldsc + 65536;

  auto issueA = [&](int t, int h) {
    char* d = ldsA + (t & 1) * 32768 + h * 16384 + w * 1024;
    glds16(aptr[h * 2 + 0] + t * 64, d);
    glds16(aptr[h * 2 + 1] + t * 64, d + 8192);
  };
  auto issueB = [&](int t, int h) {
    char* d = ldsB + (t & 1) * 32768 + h * 16384 + w * 1024;
    glds16(bptr[h * 2 + 0] + t * 64, d);
    glds16(bptr[h * 2 + 1] + t * 64, d + 8192);
  };

  f32x4 acc[8][4];
#pragma unroll
  for (int m = 0; m < 8; m++)
#pragma unroll
    for (int n = 0; n < 4; n++) acc[m][n] = (f32x4){0.f, 0.f, 0.f, 0.f};
  bf16x8 aF[4][2], bF0[2][2], bF1[2][2];

  // prologue: B0 A0 B1 A1 (16 loads); vmcnt(8) -> B0,A0 complete
  issueB(0, 0); issueB(0, 1); issueA(0, 0); issueA(0, 1);
  issueB(1, 0); issueB(1, 1); issueA(1, 0); issueA(1, 1);
  VMCNT8();
  BAR();

  for (int t = 0; t < NT; t++) {
    int abase = (t & 1) * 32768;
    int bbase = 65536 + (t & 1) * 32768;
    // ---- P1: read A(mh0)+B(nh0)
#pragma unroll
    for (int mm = 0; mm < 4; mm++)
#pragma unroll
      for (int ks = 0; ks < 2; ks++)
        aF[mm][ks] = *(const bf16x8*)(ldsc + abase + (wm * 128 + mm * 16 + fr) * 128 +
                                      ((ks * 64 + kk16) ^ xr));
#pragma unroll
    for (int nn = 0; nn < 2; nn++)
#pragma unroll
      for (int ks = 0; ks < 2; ks++)
        bF0[nn][ks] = *(const bf16x8*)(ldsc + bbase + (wn * 64 + nn * 16 + fr) * 128 +
                                       ((ks * 64 + kk16) ^ xr));
    BAR();
    __builtin_amdgcn_s_setprio(1);
#pragma unroll
    for (int mm = 0; mm < 4; mm++)
#pragma unroll
      for (int nn = 0; nn < 2; nn++)
#pragma unroll
        for (int ks = 0; ks < 2; ks++)
          acc[mm][nn] = __builtin_amdgcn_mfma_f32_16x16x32_bf16(aF[mm][ks], bF0[nn][ks], acc[mm][nn], 0, 0, 0);
    __builtin_amdgcn_s_setprio(0);
    BAR();
    // ---- P2: read B(nh1)
#pragma unroll
    for (int nn = 0; nn < 2; nn++)
#pragma unroll
      for (int ks = 0; ks < 2; ks++)
        bF1[nn][ks] = *(const bf16x8*)(ldsc + bbase + (wn * 64 + 32 + nn * 16 + fr) * 128 +
                                       ((ks * 64 + kk16) ^ xr));
    BAR();
    __builtin_amdgcn_s_setprio(1);
#pragma unroll
    for (int mm = 0; mm < 4; mm++)
#pragma unroll
      for (int nn = 0; nn < 2; nn++)
#pragma unroll
        for (int ks = 0; ks < 2; ks++)
          acc[mm][2 + nn] = __builtin_amdgcn_mfma_f32_16x16x32_bf16(aF[mm][ks], bF1[nn][ks], acc[mm][2 + nn], 0, 0, 0);
    __builtin_amdgcn_s_setprio(0);
    BAR();
    // ---- P3: read A(mh1); issue B(t+2)
#pragma unroll
    for (int mm = 0; mm < 4; mm++)
#pragma unroll
      for (int ks = 0; ks < 2; ks++)
        aF[mm][ks] = *(const bf16x8*)(ldsc + abase + (wm * 128 + 64 + mm * 16 + fr) * 128 +
                                      ((ks * 64 + kk16) ^ xr));
    if (t + 2 < NT) { issueB(t + 2, 0); issueB(t + 2, 1); }
    BAR();
    __builtin_amdgcn_s_setprio(1);
#pragma unroll
    for (int mm = 0; mm < 4; mm++)
#pragma unroll
      for (int nn = 0; nn < 2; nn++)
#pragma unroll
        for (int ks = 0; ks < 2; ks++)
          acc[4 + mm][nn] = __builtin_amdgcn_mfma_f32_16x16x32_bf16(aF[mm][ks], bF0[nn][ks], acc[4 + mm][nn], 0, 0, 0);
    __builtin_amdgcn_s_setprio(0);
    BAR();
    // ---- P4: issue A(t+2); counted wait steady / drain at tail
    if (t + 2 < NT) {
      issueA(t + 2, 0); issueA(t + 2, 1);
      VMCNT8();
    } else {
      VMCNT0();
    }
    BAR();
    __builtin_amdgcn_s_setprio(1);
#pragma unroll
    for (int mm = 0; mm < 4; mm++)
#pragma unroll
      for (int nn = 0; nn < 2; nn++)
#pragma unroll
        for (int ks = 0; ks < 2; ks++)
          acc[4 + mm][2 + nn] = __builtin_amdgcn_mfma_f32_16x16x32_bf16(aF[mm][ks], bF1[nn][ks], acc[4 + mm][2 + nn], 0, 0, 0);
    __builtin_amdgcn_s_setprio(0);
    BAR();
  }

  // ---- epilogue
  float biasN[4];
  int cN[4];
#pragma unroll
  for (int n = 0; n < 4; n++) {
    cN[n] = col0 + wn * 64 + (n >> 1) * 32 + (n & 1) * 16 + fr;
    biasN[n] = (EPI == 2) ? 0.f : bias[e * Ncols + cN[n]];
  }
  if constexpr (EPI == 0) {
#pragma unroll
    for (int m = 0; m < 8; m++) {
      int rb = rt * 256 + wm * 128 + (m >> 2) * 64 + (m & 3) * 16 + hi * 4;
#pragma unroll
      for (int j = 0; j < 4; j++) {
        int r = rb + j;
        if (r < cnt) {
#pragma unroll
          for (int n = 0; n < 4; n++) {
            float v = acc[m][n][j] + biasN[n];
            OutBf[(size_t)(off + r) * Ncols + cN[n]] = f2bf(fmaxf(v, 0.f));
          }
        }
      }
    }
  } else if constexpr (EPI == 1) {
#pragma unroll
    for (int m = 0; m < 8; m++) {
      int rb = rt * 256 + wm * 128 + (m >> 2) * 64 + (m & 3) * 16 + hi * 4;
#pragma unroll
      for (int j = 0; j < 4; j++) {
        int r = rb + j;
        if (r < cnt) {
          int idx = off + r;
          int tok = tok_list[idx];
          float g = gate_list[idx];
          size_t erow = ((size_t)e * TKN + tok) * DD;
#pragma unroll
          for (int n = 0; n < 4; n++)
            outF[erow + cN[n]] = (acc[m][n][j] + biasN[n]) * g;
        }
      }
    }
  } else {
    // raw K-partial: outF[kq][asg][DD]
#pragma unroll
    for (int m = 0; m < 8; m++) {
      int rb = rt * 256 + wm * 128 + (m >> 2) * 64 + (m & 3) * 16 + hi * 4;
#pragma unroll
      for (int j = 0; j < 4; j++) {
        int r = rb + j;
        if (r < cnt) {
          size_t prow = ((size_t)kq * NASG + off + r) * DD;
#pragma unroll
          for (int n = 0; n < 4; n++)
            outF[prow + cN[n]] = acc[m][n][j];
        }
      }
    }
  }
}

extern "C" void kernel_launch(void* const* d_in, const int* in_sizes, int n_in,
                              void* d_out, int out_size, void* d_ws, size_t ws_size,
                              hipStream_t stream) {
  const float* x     = (const float*)d_in[0];
  const float* noise = (const float*)d_in[1];
  const float* Wg    = (const float*)d_in[2];
  const float* bg    = (const float*)d_in[3];
  const float* Wn    = (const float*)d_in[4];
  const float* bn    = (const float*)d_in[5];
  const float* W1    = (const float*)d_in[6];
  const float* b1    = (const float*)d_in[7];
  const float* W2    = (const float*)d_in[8];
  const float* b2    = (const float*)d_in[9];

  float* final_out  = (float*)d_out;
  float* expert_out = final_out + (size_t)TKN * DD;
  float* gating     = expert_out + (size_t)EE * TKN * DD;

  char* ws = (char*)d_ws;
  size_t o = 0;
  auto alloc = [&](size_t bytes) {
    char* p = ws + o;
    o += bytes;
    o = (o + 255) & ~(size_t)255;
    return p;
  };
  u16*   xb        = (u16*)alloc((size_t)TKN * DD * 2);
  u16*   w1t       = (u16*)alloc((size_t)EE * HH * DD * 2);        // [E][H][D]
  u16*   w2t       = (u16*)alloc((size_t)EE * DD * HH * 2);        // [E][D][H]
  u16*   hbuf      = (u16*)alloc(((size_t)NASG + 256) * HH * 2);   // +256 pad rows
  int*   tok_list  = (int*)alloc((size_t)NASG * 4);
  float* gate_list = (float*)alloc((size_t)NASG * 4);
  int*   sel_e     = (int*)alloc((size_t)NASG * 4);
  float* sel_g     = (float*)alloc((size_t)NASG * 4);
  int*   asg_of    = (int*)alloc((size_t)NASG * 4);
  int*   counts    = (int*)alloc(256);
  int*   offsets   = (int*)alloc(256);
  int*   cursors   = (int*)alloc(256);
  int*   slots     = (int*)alloc(NSLOT * 4);
  float* part      = (float*)alloc((size_t)4 * NASG * DD * 4);     // 268 MB (last)
  bool use_split = (o <= ws_size);

  // zero only gating (router writes just the top-2 entries per token)
  hipMemsetAsync(gating, 0, (size_t)TKN * EE * sizeof(float), stream);

  router_kernel<<<TKN, 256, 0, stream>>>(x, noise, Wg, bg, Wn, bn, gating, xb, sel_e, sel_g);
  hist_scan_kernel<<<1, 256, 0, stream>>>(sel_e, counts, offsets, cursors, slots);
  build_lists_kernel<<<TKN / 256, 256, 0, stream>>>(sel_e, sel_g, cursors, tok_list,
                                                    gate_list, asg_of);
  // zero only the non-selected expert_out rows (gate==0 <=> not selected)
  zerofill_kernel<<<EE * TKN, 256, 0, stream>>>(gating, expert_out);

  transpose_cvt_kernel<<<dim3(HH / 32, DD / 64, EE), dim3(32, 8), 0, stream>>>(W1, w1t, DD, HH);
  transpose_cvt_kernel<<<dim3(DD / 32, HH / 64, EE), dim3(32, 8), 0, stream>>>(W2, w2t, HH, DD);

  // GEMM1: h = relu(x[tok] @ W1[e] + b1), K=1024, N=4096; 16 col-tiles
  gemm8_kernel<DD, DD, true, 0, 4, 0><<<8 * 9 * 16, 512, 0, stream>>>(
      xb, w1t, b1, tok_list, nullptr, counts, offsets, slots, HH, hbuf, nullptr);

  if (use_split) {
    // GEMM2 split-K x4: raw partials, then merge(+bias,gate)+combine per token
    gemm8_kernel<HH / 4, HH, false, 2, 2, 2><<<8 * 9 * 4 * 4, 512, 0, stream>>>(
        hbuf, w2t, b2, tok_list, gate_list, counts, offsets, slots, DD, nullptr, part);
    merge_combine_kernel<<<TKN, 256, 0, stream>>>(part, asg_of, sel_e, sel_g, b2,
                                                  expert_out, final_out);
  } else {
    // fallback (round-5 path): single-shot GEMM2 + combine
    gemm8_kernel<HH, HH, false, 1, 2, 0><<<8 * 9 * 4, 512, 0, stream>>>(
        hbuf, w2t, b2, tok_list, gate_list, counts, offsets, slots, DD, nullptr, expert_out);
    combine_kernel<<<TKN, 256, 0, stream>>>(expert_out, sel_e, final_out);
  }
}